// Round 7
// baseline (1904.580 us; speedup 1.0000x reference)
//
#include <hip/hip_runtime.h>

#define NB 32
#define NT 8192
#define NC 64
#define MD 64
#define NLAG 129      // 2*MD+1
#define TC 128        // time chunk per block (halved r6->r7: 2048 blocks, 8/CU)
#define RT 16         // register time tile
#define PF 16         // a-value prefetch queue depth
#define NCHUNK (NT / TC)

// Sliding-FIR body. Wave handles lags d = D0 + i, i in [0,33); acc[32] is
// garbage (dropped later) for w<3 so the inner loops need no lag guard.
//
// Ladder so far:
//  r2: loads sunk next to uses (VGPR=64, VALUBusy=13%) -> latency-bound, 316us
//  r4: av[48] upfront -> alloca demoted to scratch (+750MB spill), 1763us
//  r6: PF=16 queue + sched_barrier(0): promoted (no scratch) but allocator
//      still squeezed to 64 VGPR (8-waves/EU target) -> queue ~5 deep, 288us
//  r7: embrace the 64-VGPR tier; supply the full 8 waves/SIMD via 2x grid.
//      Even queue depth 3 x 368 cyc/SIMD-round > 900cyc HBM latency ->
//      issue-bound ~59us floor for this structure.
template<bool CHECKED>
__device__ __forceinline__ void corr_body(const float* __restrict__ Ab,
                                          const float* __restrict__ Bb,
                                          int t_start, int D0, int w,
                                          float acc[33], float& sqa, float& sqb)
{
    // unroll 1: keep one body copy (~6KB) in the 32KB I-cache
    #pragma unroll 1
    for (int t0 = t_start; t0 < t_start + TC; t0 += RT) {
        float bv[RT];
        float ap[PF];

        #pragma unroll
        for (int j = 0; j < RT; ++j) bv[j] = Bb[(t0 + j) * NC];

        // prologue: fill the a-queue for u = 0..PF-1
        #pragma unroll
        for (int u = 0; u < PF; ++u) {
            const int s = t0 + D0 + u;
            if (CHECKED) {
                ap[u] = ((unsigned)s < (unsigned)NT) ? Ab[s * NC] : 0.0f;
            } else {
                ap[u] = Ab[s * NC];
            }
        }

        if (w == 0) {
            #pragma unroll
            for (int j = 0; j < RT; ++j) sqb = fmaf(bv[j], bv[j], sqb);
        }

        // steady state: consume ap[u%PF], re-issue load for u+PF into the
        // freed slot. All queue indices compile-time after full unroll.
        // sched_barrier(0) keeps loads issued ahead of their consumers.
        #pragma unroll
        for (int u = 0; u < RT + 32; ++u) {
            const float av = ap[u % PF];
            if (u + PF < RT + 32) {
                const int s = t0 + D0 + u + PF;
                if (CHECKED) {
                    ap[u % PF] = ((unsigned)s < (unsigned)NT) ? Ab[s * NC] : 0.0f;
                } else {
                    ap[u % PF] = Ab[s * NC];
                }
            }
            // w==1 (D0=-32): u>=32 -> av == a[t0+(u-32)], always in range,
            // never zero-clamped, even in CHECKED chunks -> free sum(a^2)
            if (w == 1 && u >= 32) sqa = fmaf(av, av, sqa);

            #pragma unroll
            for (int i = 0; i < 33; ++i) {
                const int j = u - i;              // compile-time per instance
                if (j >= 0 && j < RT)
                    acc[i] = fmaf(av, bv[j], acc[i]);
            }
            __builtin_amdgcn_sched_barrier(0);
        }
    }
}

__global__ __launch_bounds__(256, 8)
void corr_kernel(const float* __restrict__ A,
                 const float* __restrict__ Bm,
                 float* __restrict__ out,   // [NB][NLAG][NC] raw corr sums (pre-zeroed)
                 float* __restrict__ sa,    // [NB][NC] sum a^2 (pre-zeroed)
                 float* __restrict__ sb)    // [NB][NC] sum b^2 (pre-zeroed)
{
    const int lane  = threadIdx.x & 63;
    const int w     = threadIdx.x >> 6;
    const int bidx  = blockIdx.x / NCHUNK;
    const int chunk = blockIdx.x % NCHUNK;
    const int t_start = chunk * TC;

    const float* Ab = A  + ((size_t)bidx * NT) * NC + lane;
    const float* Bb = Bm + ((size_t)bidx * NT) * NC + lane;
    const int D0 = -MD + w * 32;   // wave's first lag

    float acc[33];
    #pragma unroll
    for (int i = 0; i < 33; ++i) acc[i] = 0.0f;
    float sqa = 0.0f, sqb = 0.0f;

    if (chunk == 0 || chunk == NCHUNK - 1)
        corr_body<true >(Ab, Bb, t_start, D0, w, acc, sqa, sqb);
    else
        corr_body<false>(Ab, Bb, t_start, D0, w, acc, sqa, sqb);

    // epilogue: k = d + MD = w*32 + i; waves own disjoint lag bands,
    // atomics only contend across the 64 time-chunks of a batch
    float* outb = out + ((size_t)bidx * NLAG + w * 32) * NC + lane;
    #pragma unroll
    for (int i = 0; i < 33; ++i) {
        if (i < 32 || w == 3) atomicAdd(&outb[i * NC], acc[i]);
    }
    if (w == 0)      atomicAdd(&sb[bidx * NC + lane], sqb);
    else if (w == 1) atomicAdd(&sa[bidx * NC + lane], sqa);
}

__global__ void scale_kernel(float* __restrict__ out,
                             const float* __restrict__ sa,
                             const float* __restrict__ sb)
{
    const int idx = blockIdx.x * blockDim.x + threadIdx.x;
    if (idx >= NB * NLAG * NC) return;
    const int c = idx & (NC - 1);
    const int b = idx / (NLAG * NC);
    // reference: x * rsqrt(max(sum_sq, eps)) for each input, then product
    const float inv = rsqrtf(fmaxf(sa[b * NC + c], 1e-12f)) *
                      rsqrtf(fmaxf(sb[b * NC + c], 1e-12f));
    out[idx] = out[idx] * inv;
}

extern "C" void kernel_launch(void* const* d_in, const int* in_sizes, int n_in,
                              void* d_out, int out_size, void* d_ws, size_t ws_size,
                              hipStream_t stream)
{
    const float* A  = (const float*)d_in[0];
    const float* Bm = (const float*)d_in[1];
    float* out = (float*)d_out;
    float* sa  = (float*)d_ws;            // [NB*NC]
    float* sb  = sa + NB * NC;            // [NB*NC]

    // d_out / d_ws are poisoned 0xAA before every timed launch
    hipMemsetAsync(d_out, 0, (size_t)out_size * sizeof(float), stream);
    hipMemsetAsync(d_ws, 0, (size_t)(2 * NB * NC) * sizeof(float), stream);

    corr_kernel<<<dim3(NB * NCHUNK), dim3(256), 0, stream>>>(A, Bm, out, sa, sb);

    const int n_out = NB * NLAG * NC;
    scale_kernel<<<dim3((n_out + 255) / 256), dim3(256), 0, stream>>>(out, sa, sb);
}

// Round 10
// 202.010 us; speedup vs baseline: 9.4281x; 9.4281x over previous
//
#include <hip/hip_runtime.h>

#define NB 32
#define NT 8192
#define NC 64
#define MD 64
#define NLAG 129           // 2*MD+1
#define TC 64              // time rows per chunk
#define NCH 8              // chunks per block (superchunk = 512 rows)
#define RT 16              // time tile per compute step
#define AROWS 192          // circular A window = TC + 2*MD
#define NSUP (NT / (TC * NCH))   // 16 superchunks per batch

// r2/r6: global-latency + register queue -> allocator collapses queue (VGPR=64,
// VALUBusy 13-15%, 1 block/CU). r7: forcing occupancy -> VGPR=32 spill disaster.
// r8/r9/r10: LDS staging. 8 waves x 17 lags; circular 192-row A window, stage
// 64 new rows per chunk (A-traffic 1.25x); B tile shared by all 8 waves. 64KB
// LDS -> 2 blocks/CU; compute reads are 2-way-bank (free); ds latency ~120cyc
// hidden by 4 waves/SIMD + compiler lgkmcnt scheduling (m97 evidence).
__global__ __launch_bounds__(512, 4)
void corr_kernel(const float* __restrict__ A,
                 const float* __restrict__ Bm,
                 float* __restrict__ out,   // [NB][NLAG][NC] raw sums (pre-zeroed)
                 float* __restrict__ sa,    // [NB][NC] sum a^2 (pre-zeroed)
                 float* __restrict__ sb)    // [NB][NC] sum b^2 (pre-zeroed)
{
    __shared__ float As[AROWS * NC];   // 48KB
    __shared__ float Bs[TC * NC];      // 16KB

    const int tid  = threadIdx.x;
    const int lane = tid & 63;         // channel
    const int w    = tid >> 6;         // wave 0..7, lag band k = w*16 + [0,17)
    const int bidx = blockIdx.x / NSUP;
    const int sc   = blockIdx.x % NSUP;
    const int t_base = sc * (TC * NCH);

    const float* Ag = A  + (size_t)bidx * NT * NC;
    const float* Bg = Bm + (size_t)bidx * NT * NC;

    const int row0 = tid >> 4;          // 0..31 (staging row within 32-row sweep)
    const int g    = (tid & 15) * 4;    // staging channel group (float4)

    // ---- initial stage: A log rows [0,192) = t in [t_base-64, t_base+128) ----
    #pragma unroll
    for (int it = 0; it < AROWS / 32; ++it) {
        const int lr = row0 + it * 32;
        const int tt = t_base - 64 + lr;
        float4 v = make_float4(0.f, 0.f, 0.f, 0.f);
        if ((unsigned)tt < (unsigned)NT)
            v = *(const float4*)&Ag[(size_t)tt * NC + g];
        *(float4*)&As[lr * NC + g] = v;          // log==phys on first fill
    }
    #pragma unroll
    for (int it = 0; it < TC / 32; ++it) {       // B chunk 0 (always in range)
        const int r = row0 + it * 32;
        *(float4*)&Bs[r * NC + g] = *(const float4*)&Bg[(size_t)(t_base + r) * NC + g];
    }
    __syncthreads();

    float acc[17];
    #pragma unroll
    for (int i = 0; i < 17; ++i) acc[i] = 0.f;
    float sqa = 0.f, sqb = 0.f;

    for (int n = 0; n < NCH; ++n) {
        // ---- compute chunk n from LDS ----
        #pragma unroll 1
        for (int t0 = 0; t0 < TC; t0 += RT) {
            float bv[RT];
            #pragma unroll
            for (int j = 0; j < RT; ++j) bv[j] = Bs[(t0 + j) * NC + lane];
            if (w == 0) {
                #pragma unroll
                for (int j = 0; j < RT; ++j) sqb = fmaf(bv[j], bv[j], sqb);
            }
            // a log row for (i,j): L0 + (i+j), L0 = n*64 + t0 + w*16
            const int L0m = (n * TC + t0 + w * 16) % AROWS;
            #pragma unroll
            for (int u = 0; u < RT + 16; ++u) {
                int pr = L0m + u;
                if (pr >= AROWS) pr -= AROWS;
                const float av = As[pr * NC + lane];
                // w==4 (d=0 band): u<16 -> av == a[chunk row t0+u], each row once
                if (w == 4 && u < RT) sqa = fmaf(av, av, sqa);
                #pragma unroll
                for (int i = 0; i < 17; ++i) {
                    const int j = u - i;           // compile-time per instance
                    if (j >= 0 && j < RT)
                        acc[i] = fmaf(av, bv[j], acc[i]);
                }
            }
        }
        __syncthreads();

        // ---- stage chunk n+1: 64 new A rows + next B tile ----
        if (n + 1 < NCH) {
            #pragma unroll
            for (int it = 0; it < TC / 32; ++it) {
                const int r  = row0 + it * 32;              // 0..63
                const int lr = n * TC + AROWS + r;          // new log rows
                int pr = lr % AROWS;                        // overwrites oldest
                const int t = t_base + n * TC + 2 * MD + r;
                float4 v = make_float4(0.f, 0.f, 0.f, 0.f);
                if ((unsigned)t < (unsigned)NT)
                    v = *(const float4*)&Ag[(size_t)t * NC + g];
                *(float4*)&As[pr * NC + g] = v;
            }
            #pragma unroll
            for (int it = 0; it < TC / 32; ++it) {
                const int r = row0 + it * 32;
                const int t = t_base + (n + 1) * TC + r;    // always in range
                *(float4*)&Bs[r * NC + g] = *(const float4*)&Bg[(size_t)t * NC + g];
            }
            __syncthreads();
        }
    }

    // ---- epilogue: k = w*16 + i; waves 0..6 write 16 lags, wave 7 writes 17 ----
    float* outb = out + ((size_t)bidx * NLAG + w * 16) * NC + lane;
    #pragma unroll
    for (int i = 0; i < 17; ++i) {
        if (i < 16 || w == 7) atomicAdd(&outb[i * NC], acc[i]);
    }
    if (w == 0) atomicAdd(&sb[bidx * NC + lane], sqb);
    if (w == 4) atomicAdd(&sa[bidx * NC + lane], sqa);
}

__global__ void scale_kernel(float* __restrict__ out,
                             const float* __restrict__ sa,
                             const float* __restrict__ sb)
{
    const int idx = blockIdx.x * blockDim.x + threadIdx.x;
    if (idx >= NB * NLAG * NC) return;
    const int c = idx & (NC - 1);
    const int b = idx / (NLAG * NC);
    // reference: x * rsqrt(max(sum_sq, eps)) per input, then product
    const float inv = rsqrtf(fmaxf(sa[b * NC + c], 1e-12f)) *
                      rsqrtf(fmaxf(sb[b * NC + c], 1e-12f));
    out[idx] = out[idx] * inv;
}

extern "C" void kernel_launch(void* const* d_in, const int* in_sizes, int n_in,
                              void* d_out, int out_size, void* d_ws, size_t ws_size,
                              hipStream_t stream)
{
    const float* A  = (const float*)d_in[0];
    const float* Bm = (const float*)d_in[1];
    float* out = (float*)d_out;
    float* sa  = (float*)d_ws;            // [NB*NC]
    float* sb  = sa + NB * NC;            // [NB*NC]

    // d_out / d_ws are poisoned 0xAA before every timed launch
    hipMemsetAsync(d_out, 0, (size_t)out_size * sizeof(float), stream);
    hipMemsetAsync(d_ws, 0, (size_t)(2 * NB * NC) * sizeof(float), stream);

    corr_kernel<<<dim3(NB * NSUP), dim3(512), 0, stream>>>(A, Bm, out, sa, sb);

    const int n_out = NB * NLAG * NC;
    scale_kernel<<<dim3((n_out + 255) / 256), dim3(256), 0, stream>>>(out, sa, sb);
}